// Round 5
// baseline (379.830 us; speedup 1.0000x reference)
//
#include <hip/hip_runtime.h>

// CapsuleBlock dynamic routing, MI355X — R5.
// x: [64, 2048, 8] f32; W: [2048, 16, 8, 16] f32; out: [64, 16, 16] f32.
// R4 lesson: 2x occupancy gained ~nothing -> per-wave serial chain (6 swizzle
// + 2 LDS per pair) and W VMEM rate are the suspects, not raw TLP.
// R5: BGW=8 (W frag reused 8x), softmax cross-lane via DPP (quad_perm xor1/2,
// row_ror 4/8) leaving only xor16/xor32 on DS pipe, ov in registers,
// squash fused into final reduce.

#define B_    64
#define NIN   2048
#define NW    4                  // waves per block
#define BGW   8                  // b's per block (shared by all waves)
#define NSTEP 4                  // n's per wave
#define NCB   (NW * NSTEP)       // 16 n per block
#define GX    (NIN / NCB)        // 128
#define GY    (B_ / BGW)         // 8
#define NSLC  (GX * NW)          // 512 partial slices per b

// v + dpp(v). CTRL: 0xB1 = quad_perm xor1, 0x4E = quad_perm xor2,
// 0x124 = row_ror:4, 0x128 = row_ror:8 (within row of 16).
template<int CTRL>
__device__ __forceinline__ float dpp_add(float v) {
    int t = __builtin_amdgcn_update_dpp(0, __float_as_int(v), CTRL, 0xF, 0xF, true);
    return v + __int_as_float(t);
}

// MODE 0: s0 = sum_n hat                 (uniform c; 1/16 applied in MODE1/2)
// MODE 1: ov = squash(s0/16);            s1 = sum_n softmax_k(hat.ov)*hat
// MODE 2: ov = squash(s0/16)+squash(s1); s2 = sum_n softmax_k(hat.ov)*hat
template<int MODE>
__global__ __launch_bounds__(256, 4) void k_pass(const float* __restrict__ x,
                                                 const float* __restrict__ W,
                                                 const float* __restrict__ s0,
                                                 const float* __restrict__ s1,
                                                 float* __restrict__ partial) {
    __shared__ float4 xt[BGW][NCB][2];   // 4 KB
    __shared__ float4 ovs[BGW * 64];     // 8 KB

    const int tid  = threadIdx.x;
    const int lane = tid & 63;
    const int w    = tid >> 6;
    const int k    = lane >> 2;
    const int o4   = lane & 3;
    const int nbase = blockIdx.x * NCB;
    const int b0    = blockIdx.y * BGW;

    // Stage x tile: 256 float4, one per thread, coalesced.
    {
        int bl = tid >> 5, r = tid & 31, nn = r >> 1, j = r & 1;
        xt[bl][nn][j] =
            *(const float4*)(x + ((size_t)(b0 + bl) * NIN + nbase + nn) * 8 + j * 4);
    }

    if (MODE >= 1) {
        // Each wave computes squashed output vectors for 2 of the 8 b's.
#pragma unroll
        for (int r = 0; r < 2; ++r) {
            int bl = w * 2 + r;
            int b  = b0 + bl;
            float4 v = *(const float4*)&s0[b * 256 + lane * 4];
            v.x *= 0.0625f; v.y *= 0.0625f; v.z *= 0.0625f; v.w *= 0.0625f;
            float sq = v.x*v.x + v.y*v.y + v.z*v.z + v.w*v.w;
            sq = dpp_add<0xB1>(sq);
            sq = dpp_add<0x4E>(sq);                  // sum over k-row's 16 o's
            float sc = sq / (1.f + sq) * rsqrtf(sq);
            float4 o = make_float4(v.x*sc, v.y*sc, v.z*sc, v.w*sc);
            if (MODE == 2) {
                float4 u = *(const float4*)&s1[b * 256 + lane * 4];
                float q2 = u.x*u.x + u.y*u.y + u.z*u.z + u.w*u.w;
                q2 = dpp_add<0xB1>(q2);
                q2 = dpp_add<0x4E>(q2);
                float sc2 = q2 / (1.f + q2) * rsqrtf(q2);
                o.x = fmaf(u.x, sc2, o.x);
                o.y = fmaf(u.y, sc2, o.y);
                o.z = fmaf(u.z, sc2, o.z);
                o.w = fmaf(u.w, sc2, o.w);
            }
            ovs[bl * 64 + lane] = o;
        }
    }
    __syncthreads();

    // ov registers: j-invariant, load once (MODE>=1). 32 VGPRs.
    float4 ov[BGW];
    if (MODE >= 1) {
#pragma unroll
        for (int i = 0; i < BGW; ++i) ov[i] = ovs[i * 64 + lane];
    }

    float4 acc[BGW];
#pragma unroll
    for (int i = 0; i < BGW; ++i) acc[i] = make_float4(0.f, 0.f, 0.f, 0.f);

#pragma unroll
    for (int jj = 0; jj < NSTEP; ++jj) {
        const int n = nbase + w * NSTEP + jj;
        const float* wp = W + ((size_t)n * 16 + k) * 128 + o4 * 4;
        float4 wf[8];
#pragma unroll
        for (int d = 0; d < 8; ++d) wf[d] = *(const float4*)(wp + d * 16);

#pragma unroll
        for (int i = 0; i < BGW; ++i) {
            float4 xa = xt[i][w * NSTEP + jj][0];    // wave-uniform broadcast
            float4 xb = xt[i][w * NSTEP + jj][1];
            float xs[8] = {xa.x, xa.y, xa.z, xa.w, xb.x, xb.y, xb.z, xb.w};
            float4 h = make_float4(0.f, 0.f, 0.f, 0.f);
#pragma unroll
            for (int d = 0; d < 8; ++d) {
                h.x = fmaf(xs[d], wf[d].x, h.x);
                h.y = fmaf(xs[d], wf[d].y, h.y);
                h.z = fmaf(xs[d], wf[d].z, h.z);
                h.w = fmaf(xs[d], wf[d].w, h.w);
            }
            if (MODE >= 1) {
                float part = h.x * ov[i].x;
                part = fmaf(h.y, ov[i].y, part);
                part = fmaf(h.z, ov[i].z, part);
                part = fmaf(h.w, ov[i].w, part);
                part = dpp_add<0xB1>(part);
                part = dpp_add<0x4E>(part);          // bias_k, quad-uniform
                // |bias| <~ 20 << 88: raw exp safe in f32 (validated R4).
                float e = __expf(part);
                float es = e;
                es = dpp_add<0x124>(es);             // + ror4  (k within row)
                es = dpp_add<0x128>(es);             // + ror8 -> row-sum of 4 k
                es += __shfl_xor(es, 16);
                es += __shfl_xor(es, 32);            // full sum over 16 k
                float c = __fdividef(e, es);
                h.x *= c; h.y *= c; h.z *= c; h.w *= c;
            }
            acc[i].x += h.x; acc[i].y += h.y; acc[i].z += h.z; acc[i].w += h.w;
        }
    }

    // Wave-private partial slices, coalesced 1KB stores.
    const int sidx = blockIdx.x * NW + w;
#pragma unroll
    for (int i = 0; i < BGW; ++i)
        *(float4*)&partial[((size_t)(b0 + i) * NSLC + sidx) * 256 + lane * 4] = acc[i];
}

// Sum NSLC slices per b; 4 waves split slices, LDS combine.
// SQUASH=1: apply squash over o and write final output.
template<int SQUASH>
__global__ __launch_bounds__(256) void k_reduce(const float* __restrict__ partial,
                                                float* __restrict__ s) {
    const int b = blockIdx.x;
    const int lane = threadIdx.x & 63;
    const int w = threadIdx.x >> 6;
    const float* base = partial + (size_t)b * NSLC * 256 + lane * 4;
    float4 a = make_float4(0.f, 0.f, 0.f, 0.f);
#pragma unroll 8
    for (int sl = 0; sl < NSLC / 4; ++sl) {
        float4 v = *(const float4*)(base + (size_t)(w * (NSLC / 4) + sl) * 256);
        a.x += v.x; a.y += v.y; a.z += v.z; a.w += v.w;
    }
    __shared__ float4 red[4][64];
    red[w][lane] = a;
    __syncthreads();
    if (w == 0) {
        float4 r1 = red[1][lane], r2 = red[2][lane], r3 = red[3][lane];
        a.x += r1.x + r2.x + r3.x;
        a.y += r1.y + r2.y + r3.y;
        a.z += r1.z + r2.z + r3.z;
        a.w += r1.w + r2.w + r3.w;
        if (SQUASH) {
            float sq = a.x*a.x + a.y*a.y + a.z*a.z + a.w*a.w;
            sq = dpp_add<0xB1>(sq);
            sq = dpp_add<0x4E>(sq);                  // sum over 16 o's of this k
            float sc = sq / (1.f + sq) * rsqrtf(sq);
            a.x *= sc; a.y *= sc; a.z *= sc; a.w *= sc;
        }
        *(float4*)&s[b * 256 + lane * 4] = a;
    }
}

extern "C" void kernel_launch(void* const* d_in, const int* in_sizes, int n_in,
                              void* d_out, int out_size, void* d_ws, size_t ws_size,
                              hipStream_t stream) {
    const float* x = (const float*)d_in[0];
    const float* W = (const float*)d_in[1];
    float* out = (float*)d_out;

    float* s0 = (float*)d_ws;                 // [64][256]
    float* s1 = s0 + B_ * 256;
    float* partial = s1 + B_ * 256;           // [64][512][256] f32 = 32 MB

    dim3 grid(GX, GY);                        // (128, 8) = 1024 blocks

    k_pass<0><<<grid, 256, 0, stream>>>(x, W, nullptr, nullptr, partial);
    k_reduce<0><<<B_, 256, 0, stream>>>(partial, s0);
    k_pass<1><<<grid, 256, 0, stream>>>(x, W, s0, nullptr, partial);
    k_reduce<0><<<B_, 256, 0, stream>>>(partial, s1);
    k_pass<2><<<grid, 256, 0, stream>>>(x, W, s0, s1, partial);
    k_reduce<1><<<B_, 256, 0, stream>>>(partial, out);
}

// Round 7
// 336.796 us; speedup vs baseline: 1.1278x; 1.1278x over previous
//
#include <hip/hip_runtime.h>

// CapsuleBlock dynamic routing, MI355X — R6 (resubmit; R6 bench was an
// infra failure: GPU acquisition timeout, no data).
// x: [64, 2048, 8] f32; W: [2048, 16, 8, 16] f32; out: [64, 16, 16] f32.
// R5 lesson: b-major scattered partial stores (512KB stride) -> 190MB FETCH /
// 156MB WRITE per pass (L2/L3 thrash + RFO amplification). R3/R4's block-
// contiguous stores were clean (4MB). R6 = R5 compute (DPP softmax, BGW=8,
// ov in regs, 1024 blocks) + R3-style in-block LDS reduce + contiguous 8KB
// block partial (8MB total).

#define B_    64
#define NIN   2048
#define NW    4                  // waves per block
#define BGW   8                  // b's per block (shared by all waves)
#define NSTEP 4                  // n's per wave
#define NCB   (NW * NSTEP)       // 16 n per block
#define GX    (NIN / NCB)        // 128
#define GY    (B_ / BGW)         // 8

// v + dpp(v). CTRL: 0xB1 = quad_perm xor1, 0x4E = quad_perm xor2,
// 0x124 = row_ror:4, 0x128 = row_ror:8 (row = 16 lanes).
template<int CTRL>
__device__ __forceinline__ float dpp_add(float v) {
    int t = __builtin_amdgcn_update_dpp(0, __float_as_int(v), CTRL, 0xF, 0xF, true);
    return v + __int_as_float(t);
}

// MODE 0: s0 = sum_n hat                 (uniform c; 1/16 applied in MODE1/2)
// MODE 1: ov = squash(s0/16);            s1 = sum_n softmax_k(hat.ov)*hat
// MODE 2: ov = squash(s0/16)+squash(s1); s2 = sum_n softmax_k(hat.ov)*hat
template<int MODE>
__global__ __launch_bounds__(256, 4) void k_pass(const float* __restrict__ x,
                                                 const float* __restrict__ W,
                                                 const float* __restrict__ s0,
                                                 const float* __restrict__ s1,
                                                 float* __restrict__ partial) {
    __shared__ union {
        struct {
            float4 xt[BGW][NCB][2];      // 4 KB
            float4 ovs[BGW * 64];        // 8 KB
        } in;
        float4 red[BGW][NW][64];         // 32 KB (overlays in; barrier-guarded)
    } sm;

    const int tid  = threadIdx.x;
    const int lane = tid & 63;
    const int w    = tid >> 6;
    const int k    = lane >> 2;
    const int o4   = lane & 3;
    const int nbase = blockIdx.x * NCB;
    const int b0    = blockIdx.y * BGW;

    // Stage x tile: 256 float4, one per thread, coalesced.
    {
        int bl = tid >> 5, r = tid & 31, nn = r >> 1, j = r & 1;
        sm.in.xt[bl][nn][j] =
            *(const float4*)(x + ((size_t)(b0 + bl) * NIN + nbase + nn) * 8 + j * 4);
    }

    if (MODE >= 1) {
        // Each wave computes squashed output vectors for 2 of the 8 b's.
#pragma unroll
        for (int r = 0; r < 2; ++r) {
            int bl = w * 2 + r;
            int b  = b0 + bl;
            float4 v = *(const float4*)&s0[b * 256 + lane * 4];
            v.x *= 0.0625f; v.y *= 0.0625f; v.z *= 0.0625f; v.w *= 0.0625f;
            float sq = v.x*v.x + v.y*v.y + v.z*v.z + v.w*v.w;
            sq = dpp_add<0xB1>(sq);
            sq = dpp_add<0x4E>(sq);                  // sum over k-row's 16 o's
            float sc = sq / (1.f + sq) * rsqrtf(sq);
            float4 o = make_float4(v.x*sc, v.y*sc, v.z*sc, v.w*sc);
            if (MODE == 2) {
                float4 u = *(const float4*)&s1[b * 256 + lane * 4];
                float q2 = u.x*u.x + u.y*u.y + u.z*u.z + u.w*u.w;
                q2 = dpp_add<0xB1>(q2);
                q2 = dpp_add<0x4E>(q2);
                float sc2 = q2 / (1.f + q2) * rsqrtf(q2);
                o.x = fmaf(u.x, sc2, o.x);
                o.y = fmaf(u.y, sc2, o.y);
                o.z = fmaf(u.z, sc2, o.z);
                o.w = fmaf(u.w, sc2, o.w);
            }
            sm.in.ovs[bl * 64 + lane] = o;
        }
    }
    __syncthreads();

    // ov registers: j-invariant, load once (MODE>=1). 32 VGPRs.
    float4 ov[BGW];
    if (MODE >= 1) {
#pragma unroll
        for (int i = 0; i < BGW; ++i) ov[i] = sm.in.ovs[i * 64 + lane];
    }

    float4 acc[BGW];
#pragma unroll
    for (int i = 0; i < BGW; ++i) acc[i] = make_float4(0.f, 0.f, 0.f, 0.f);

#pragma unroll
    for (int jj = 0; jj < NSTEP; ++jj) {
        const int n = nbase + w * NSTEP + jj;
        const float* wp = W + ((size_t)n * 16 + k) * 128 + o4 * 4;
        float4 wf[8];
#pragma unroll
        for (int d = 0; d < 8; ++d) wf[d] = *(const float4*)(wp + d * 16);

#pragma unroll
        for (int i = 0; i < BGW; ++i) {
            float4 xa = sm.in.xt[i][w * NSTEP + jj][0];   // wave-uniform bcast
            float4 xb = sm.in.xt[i][w * NSTEP + jj][1];
            float xs[8] = {xa.x, xa.y, xa.z, xa.w, xb.x, xb.y, xb.z, xb.w};
            float4 h = make_float4(0.f, 0.f, 0.f, 0.f);
#pragma unroll
            for (int d = 0; d < 8; ++d) {
                h.x = fmaf(xs[d], wf[d].x, h.x);
                h.y = fmaf(xs[d], wf[d].y, h.y);
                h.z = fmaf(xs[d], wf[d].z, h.z);
                h.w = fmaf(xs[d], wf[d].w, h.w);
            }
            if (MODE >= 1) {
                float part = h.x * ov[i].x;
                part = fmaf(h.y, ov[i].y, part);
                part = fmaf(h.z, ov[i].z, part);
                part = fmaf(h.w, ov[i].w, part);
                part = dpp_add<0xB1>(part);
                part = dpp_add<0x4E>(part);          // bias_k, quad-uniform
                // |bias| <~ 20 << 88: raw exp safe in f32 (validated R4/R5).
                float e = __expf(part);
                float es = e;
                es = dpp_add<0x124>(es);             // + ror4
                es = dpp_add<0x128>(es);             // -> row-sum of 4 k's
                es += __shfl_xor(es, 16);
                es += __shfl_xor(es, 32);            // full sum over 16 k's
                float c = __fdividef(e, es);
                h.x *= c; h.y *= c; h.z *= c; h.w *= c;
            }
            acc[i].x += h.x; acc[i].y += h.y; acc[i].z += h.z; acc[i].w += h.w;
        }
    }

    // Cross-wave LDS reduce -> ONE contiguous 8 KB block partial.
    __syncthreads();                       // all xt reads done; safe to overlay
#pragma unroll
    for (int i = 0; i < BGW; ++i) sm.red[i][w][lane] = acc[i];
    __syncthreads();

    float* pbase = partial + (size_t)(blockIdx.y * GX + blockIdx.x) * (BGW * 256);
#pragma unroll
    for (int r = 0; r < 2; ++r) {
        int q  = r * 256 + tid;            // float4 index 0..511
        int bl = q >> 6, ln = q & 63;
        float4 a  = sm.red[bl][0][ln];
        float4 c1 = sm.red[bl][1][ln];
        float4 c2 = sm.red[bl][2][ln];
        float4 c3 = sm.red[bl][3][ln];
        a.x += c1.x + c2.x + c3.x;
        a.y += c1.y + c2.y + c3.y;
        a.z += c1.z + c2.z + c3.z;
        a.w += c1.w + c2.w + c3.w;
        *(float4*)&pbase[q * 4] = a;
    }
}

// s[b][t] = sum over x of partial[(y*GX+x)*2048 + bl*256 + t], b = y*8+bl.
// 4 waves split the x-range, LDS combine. SQUASH=1: squash over o, write out.
template<int SQUASH>
__global__ __launch_bounds__(256) void k_reduce(const float* __restrict__ partial,
                                                float* __restrict__ s) {
    const int b = blockIdx.x;
    const int y = b >> 3, bl = b & 7;
    const int lane = threadIdx.x & 63;
    const int w = threadIdx.x >> 6;
    const float* base = partial + ((size_t)y * GX * BGW + bl) * 256 + lane * 4;
    float4 a = make_float4(0.f, 0.f, 0.f, 0.f);
#pragma unroll 8
    for (int xx = 0; xx < GX / 4; ++xx) {
        float4 v = *(const float4*)(base + (size_t)(w * (GX / 4) + xx) * (BGW * 256));
        a.x += v.x; a.y += v.y; a.z += v.z; a.w += v.w;
    }
    __shared__ float4 red[4][64];
    red[w][lane] = a;
    __syncthreads();
    if (w == 0) {
        float4 r1 = red[1][lane], r2 = red[2][lane], r3 = red[3][lane];
        a.x += r1.x + r2.x + r3.x;
        a.y += r1.y + r2.y + r3.y;
        a.z += r1.z + r2.z + r3.z;
        a.w += r1.w + r2.w + r3.w;
        if (SQUASH) {
            float sq = a.x*a.x + a.y*a.y + a.z*a.z + a.w*a.w;
            sq = dpp_add<0xB1>(sq);
            sq = dpp_add<0x4E>(sq);                  // sum over 16 o's of this k
            float sc = sq / (1.f + sq) * rsqrtf(sq);
            a.x *= sc; a.y *= sc; a.z *= sc; a.w *= sc;
        }
        *(float4*)&s[b * 256 + lane * 4] = a;
    }
}

extern "C" void kernel_launch(void* const* d_in, const int* in_sizes, int n_in,
                              void* d_out, int out_size, void* d_ws, size_t ws_size,
                              hipStream_t stream) {
    const float* x = (const float*)d_in[0];
    const float* W = (const float*)d_in[1];
    float* out = (float*)d_out;

    float* s0 = (float*)d_ws;                 // [64][256]
    float* s1 = s0 + B_ * 256;
    float* partial = s1 + B_ * 256;           // 1024 blocks x 8 KB = 8 MB

    dim3 grid(GX, GY);                        // (128, 8) = 1024 blocks

    k_pass<0><<<grid, 256, 0, stream>>>(x, W, nullptr, nullptr, partial);
    k_reduce<0><<<B_, 256, 0, stream>>>(partial, s0);
    k_pass<1><<<grid, 256, 0, stream>>>(x, W, s0, nullptr, partial);
    k_reduce<0><<<B_, 256, 0, stream>>>(partial, s1);
    k_pass<2><<<grid, 256, 0, stream>>>(x, W, s0, s1, partial);
    k_reduce<1><<<B_, 256, 0, stream>>>(partial, out);
}

// Round 8
// 316.299 us; speedup vs baseline: 1.2009x; 1.0648x over previous
//
#include <hip/hip_runtime.h>

// CapsuleBlock dynamic routing, MI355X — R8.
// x: [64, 2048, 8] f32; W: [2048, 16, 8, 16] f32; out: [64, 16, 16] f32.
// R5-R7 post-mortem: ov[8]+acc[8]+wf[8] (~110 live VGPR) vs launch_bounds cap
// 128 -> compiler SPILLED to scratch; scratch reloads = 237MB FETCH / 168MB
// WRITE per pass, VALUBusy 10%. (R5's "scattered store" theory was wrong —
// R6/R7 fixed stores, traffic stayed.)
// R8: BGW=4 (wf 32 + ov 16 + acc 16 + temps ~= 95 regs, NO spill), grid 2048
// blocks (5-6 blocks/CU), DPP quad/row reduces, 2 shfl/pair on DS pipe,
// cross-wave LDS reduce -> 4KB contiguous partial/block (8MB total).

#define B_    64
#define NIN   2048
#define NW    4                  // waves per block
#define BGW   4                  // b's per block (all waves share them)
#define NSTEP 4                  // n's per wave
#define NCB   (NW * NSTEP)       // 16 n per block
#define GX    (NIN / NCB)        // 128
#define GY    (B_ / BGW)         // 16

// v + dpp(v). CTRL: 0xB1 = quad_perm xor1, 0x4E = quad_perm xor2,
// 0x124 = row_ror:4, 0x128 = row_ror:8 (row = 16 lanes).
template<int CTRL>
__device__ __forceinline__ float dpp_add(float v) {
    int t = __builtin_amdgcn_update_dpp(0, __float_as_int(v), CTRL, 0xF, 0xF, true);
    return v + __int_as_float(t);
}

// MODE 0: s0 = sum_n hat                 (uniform c; 1/16 applied in MODE1/2)
// MODE 1: ov = squash(s0/16);            s1 = sum_n softmax_k(hat.ov)*hat
// MODE 2: ov = squash(s0/16)+squash(s1); s2 = sum_n softmax_k(hat.ov)*hat
template<int MODE>
__global__ __launch_bounds__(256, 4) void k_pass(const float* __restrict__ x,
                                                 const float* __restrict__ W,
                                                 const float* __restrict__ s0,
                                                 const float* __restrict__ s1,
                                                 float* __restrict__ partial) {
    __shared__ float4 xt[BGW][NCB][2];     // 2 KB
    __shared__ float4 ovs[BGW][64];        // 4 KB
    __shared__ float4 red[NW][BGW][64];    // 16 KB

    const int tid  = threadIdx.x;
    const int lane = tid & 63;
    const int w    = tid >> 6;
    const int k    = lane >> 2;
    const int o4   = lane & 3;
    const int nbase = blockIdx.x * NCB;
    const int b0    = blockIdx.y * BGW;

    // Stage x tile: 128 float4 (4 b x 16 n x 2), coalesced, half threads.
    if (tid < 128) {
        int bl = tid >> 5, r = tid & 31, nn = r >> 1, j = r & 1;
        xt[bl][nn][j] =
            *(const float4*)(x + ((size_t)(b0 + bl) * NIN + nbase + nn) * 8 + j * 4);
    }

    if (MODE >= 1) {
        // Wave w computes the squashed output vector for b0+w.
        int b = b0 + w;
        float4 v = *(const float4*)&s0[b * 256 + lane * 4];
        v.x *= 0.0625f; v.y *= 0.0625f; v.z *= 0.0625f; v.w *= 0.0625f;
        float sq = v.x*v.x + v.y*v.y + v.z*v.z + v.w*v.w;
        sq = dpp_add<0xB1>(sq);
        sq = dpp_add<0x4E>(sq);                  // sum over this k-row's 16 o's
        float sc = sq / (1.f + sq) * rsqrtf(sq);
        float4 o = make_float4(v.x*sc, v.y*sc, v.z*sc, v.w*sc);
        if (MODE == 2) {
            float4 u = *(const float4*)&s1[b * 256 + lane * 4];
            float q2 = u.x*u.x + u.y*u.y + u.z*u.z + u.w*u.w;
            q2 = dpp_add<0xB1>(q2);
            q2 = dpp_add<0x4E>(q2);
            float sc2 = q2 / (1.f + q2) * rsqrtf(q2);
            o.x = fmaf(u.x, sc2, o.x);
            o.y = fmaf(u.y, sc2, o.y);
            o.z = fmaf(u.z, sc2, o.z);
            o.w = fmaf(u.w, sc2, o.w);
        }
        ovs[w][lane] = o;
    }
    __syncthreads();

    // ov in regs: 16 VGPRs, loop-invariant.
    float4 ov[BGW];
    if (MODE >= 1) {
#pragma unroll
        for (int i = 0; i < BGW; ++i) ov[i] = ovs[i][lane];
    }

    float4 acc[BGW];
#pragma unroll
    for (int i = 0; i < BGW; ++i) acc[i] = make_float4(0.f, 0.f, 0.f, 0.f);

#pragma unroll
    for (int jj = 0; jj < NSTEP; ++jj) {
        const int n = nbase + w * NSTEP + jj;
        const float* wp = W + ((size_t)n * 16 + k) * 128 + o4 * 4;
        float4 wf[8];
#pragma unroll
        for (int d = 0; d < 8; ++d) wf[d] = *(const float4*)(wp + d * 16);

#pragma unroll
        for (int i = 0; i < BGW; ++i) {
            float4 xa = xt[i][w * NSTEP + jj][0];    // wave-uniform broadcast
            float4 xb = xt[i][w * NSTEP + jj][1];
            float4 h = make_float4(0.f, 0.f, 0.f, 0.f);
            h.x = fmaf(xa.x, wf[0].x, h.x); h.y = fmaf(xa.x, wf[0].y, h.y);
            h.z = fmaf(xa.x, wf[0].z, h.z); h.w = fmaf(xa.x, wf[0].w, h.w);
            h.x = fmaf(xa.y, wf[1].x, h.x); h.y = fmaf(xa.y, wf[1].y, h.y);
            h.z = fmaf(xa.y, wf[1].z, h.z); h.w = fmaf(xa.y, wf[1].w, h.w);
            h.x = fmaf(xa.z, wf[2].x, h.x); h.y = fmaf(xa.z, wf[2].y, h.y);
            h.z = fmaf(xa.z, wf[2].z, h.z); h.w = fmaf(xa.z, wf[2].w, h.w);
            h.x = fmaf(xa.w, wf[3].x, h.x); h.y = fmaf(xa.w, wf[3].y, h.y);
            h.z = fmaf(xa.w, wf[3].z, h.z); h.w = fmaf(xa.w, wf[3].w, h.w);
            h.x = fmaf(xb.x, wf[4].x, h.x); h.y = fmaf(xb.x, wf[4].y, h.y);
            h.z = fmaf(xb.x, wf[4].z, h.z); h.w = fmaf(xb.x, wf[4].w, h.w);
            h.x = fmaf(xb.y, wf[5].x, h.x); h.y = fmaf(xb.y, wf[5].y, h.y);
            h.z = fmaf(xb.y, wf[5].z, h.z); h.w = fmaf(xb.y, wf[5].w, h.w);
            h.x = fmaf(xb.z, wf[6].x, h.x); h.y = fmaf(xb.z, wf[6].y, h.y);
            h.z = fmaf(xb.z, wf[6].z, h.z); h.w = fmaf(xb.z, wf[6].w, h.w);
            h.x = fmaf(xb.w, wf[7].x, h.x); h.y = fmaf(xb.w, wf[7].y, h.y);
            h.z = fmaf(xb.w, wf[7].z, h.z); h.w = fmaf(xb.w, wf[7].w, h.w);

            if (MODE >= 1) {
                float part = h.x * ov[i].x;
                part = fmaf(h.y, ov[i].y, part);
                part = fmaf(h.z, ov[i].z, part);
                part = fmaf(h.w, ov[i].w, part);
                part = dpp_add<0xB1>(part);
                part = dpp_add<0x4E>(part);          // bias_k, quad-uniform
                // |bias| <~ 20 << 88: raw exp safe in f32 (validated R3-R7).
                float e = __expf(part);
                float es = e;
                es = dpp_add<0x124>(es);             // + ror4
                es = dpp_add<0x128>(es);             // -> sum of row's 4 k's
                es += __shfl_xor(es, 16);
                es += __shfl_xor(es, 32);            // full sum over 16 k's
                float c = __fdividef(e, es);
                h.x *= c; h.y *= c; h.z *= c; h.w *= c;
            }
            acc[i].x += h.x; acc[i].y += h.y; acc[i].z += h.z; acc[i].w += h.w;
        }
    }

    // Cross-wave reduce (4 waves hold different n-partials of same 4 b's).
#pragma unroll
    for (int i = 0; i < BGW; ++i) red[w][i][lane] = acc[i];
    __syncthreads();

    // 256 threads -> 256 float4 outputs; ONE contiguous 4 KB block partial.
    {
        int bl = tid >> 6, ln = tid & 63;
        float4 a  = red[0][bl][ln];
        float4 c1 = red[1][bl][ln];
        float4 c2 = red[2][bl][ln];
        float4 c3 = red[3][bl][ln];
        a.x += c1.x + c2.x + c3.x;
        a.y += c1.y + c2.y + c3.y;
        a.z += c1.z + c2.z + c3.z;
        a.w += c1.w + c2.w + c3.w;
        float* pbase = partial + (size_t)(blockIdx.y * GX + blockIdx.x) * (BGW * 256);
        *(float4*)&pbase[tid * 4] = a;
    }
}

// s[b][t] = sum over bx of partial[(by*GX+bx)*1024 + bl*256 + t], b=by*4+bl.
// 4 waves split the bx-range, LDS combine. SQUASH=1: squash over o, write out.
template<int SQUASH>
__global__ __launch_bounds__(256) void k_reduce(const float* __restrict__ partial,
                                                float* __restrict__ s) {
    const int b = blockIdx.x;
    const int by = b >> 2, bl = b & 3;
    const int lane = threadIdx.x & 63;
    const int w = threadIdx.x >> 6;
    const float* base = partial + ((size_t)by * GX) * (BGW * 256) + bl * 256 + lane * 4;
    float4 a = make_float4(0.f, 0.f, 0.f, 0.f);
#pragma unroll 8
    for (int xx = 0; xx < GX / 4; ++xx) {
        float4 v = *(const float4*)(base + (size_t)(w * (GX / 4) + xx) * (BGW * 256));
        a.x += v.x; a.y += v.y; a.z += v.z; a.w += v.w;
    }
    __shared__ float4 red[4][64];
    red[w][lane] = a;
    __syncthreads();
    if (w == 0) {
        float4 r1 = red[1][lane], r2 = red[2][lane], r3 = red[3][lane];
        a.x += r1.x + r2.x + r3.x;
        a.y += r1.y + r2.y + r3.y;
        a.z += r1.z + r2.z + r3.z;
        a.w += r1.w + r2.w + r3.w;
        if (SQUASH) {
            float sq = a.x*a.x + a.y*a.y + a.z*a.z + a.w*a.w;
            sq = dpp_add<0xB1>(sq);
            sq = dpp_add<0x4E>(sq);                  // sum over 16 o's of this k
            float sc = sq / (1.f + sq) * rsqrtf(sq);
            a.x *= sc; a.y *= sc; a.z *= sc; a.w *= sc;
        }
        *(float4*)&s[b * 256 + lane * 4] = a;
    }
}

extern "C" void kernel_launch(void* const* d_in, const int* in_sizes, int n_in,
                              void* d_out, int out_size, void* d_ws, size_t ws_size,
                              hipStream_t stream) {
    const float* x = (const float*)d_in[0];
    const float* W = (const float*)d_in[1];
    float* out = (float*)d_out;

    float* s0 = (float*)d_ws;                 // [64][256]
    float* s1 = s0 + B_ * 256;
    float* partial = s1 + B_ * 256;           // 2048 blocks x 4 KB = 8 MB

    dim3 grid(GX, GY);                        // (128, 16) = 2048 blocks

    k_pass<0><<<grid, 256, 0, stream>>>(x, W, nullptr, nullptr, partial);
    k_reduce<0><<<B_, 256, 0, stream>>>(partial, s0);
    k_pass<1><<<grid, 256, 0, stream>>>(x, W, s0, nullptr, partial);
    k_reduce<0><<<B_, 256, 0, stream>>>(partial, s1);
    k_pass<2><<<grid, 256, 0, stream>>>(x, W, s0, s1, partial);
    k_reduce<1><<<B_, 256, 0, stream>>>(partial, out);
}

// Round 9
// 139.877 us; speedup vs baseline: 2.7155x; 2.2613x over previous
//
#include <hip/hip_runtime.h>

// CapsuleBlock dynamic routing, MI355X — R9.
// x: [64, 2048, 8] f32; W: [2048, 16, 8, 16] f32; out: [64, 16, 16] f32.
// R5-R8 post-mortem: __launch_bounds__(256, 4) pinned the allocator to 64
// VGPRs (512/8waves) — every kernel with that attribute shows VGPR_Count=64
// and 200-500MB of scratch spill traffic (R5/R7/R8). R3's plain
// __launch_bounds__(256) allocated 68 VGPRs with clean counters (FETCH 10.5MB,
// WRITE 4MB). R9 = R8 with the min-waves arg REMOVED (single-variable fix).

#define B_    64
#define NIN   2048
#define NW    4                  // waves per block
#define BGW   4                  // b's per block (all waves share them)
#define NSTEP 4                  // n's per wave
#define NCB   (NW * NSTEP)       // 16 n per block
#define GX    (NIN / NCB)        // 128
#define GY    (B_ / BGW)         // 16

// v + dpp(v). CTRL: 0xB1 = quad_perm xor1, 0x4E = quad_perm xor2,
// 0x124 = row_ror:4, 0x128 = row_ror:8 (row = 16 lanes).
template<int CTRL>
__device__ __forceinline__ float dpp_add(float v) {
    int t = __builtin_amdgcn_update_dpp(0, __float_as_int(v), CTRL, 0xF, 0xF, true);
    return v + __int_as_float(t);
}

// MODE 0: s0 = sum_n hat                 (uniform c; 1/16 applied in MODE1/2)
// MODE 1: ov = squash(s0/16);            s1 = sum_n softmax_k(hat.ov)*hat
// MODE 2: ov = squash(s0/16)+squash(s1); s2 = sum_n softmax_k(hat.ov)*hat
template<int MODE>
__global__ __launch_bounds__(256) void k_pass(const float* __restrict__ x,
                                              const float* __restrict__ W,
                                              const float* __restrict__ s0,
                                              const float* __restrict__ s1,
                                              float* __restrict__ partial) {
    __shared__ float4 xt[BGW][NCB][2];     // 2 KB
    __shared__ float4 ovs[BGW][64];        // 4 KB
    __shared__ float4 red[NW][BGW][64];    // 16 KB

    const int tid  = threadIdx.x;
    const int lane = tid & 63;
    const int w    = tid >> 6;
    const int k    = lane >> 2;
    const int o4   = lane & 3;
    const int nbase = blockIdx.x * NCB;
    const int b0    = blockIdx.y * BGW;

    // Stage x tile: 128 float4 (4 b x 16 n x 2), coalesced, half threads.
    if (tid < 128) {
        int bl = tid >> 5, r = tid & 31, nn = r >> 1, j = r & 1;
        xt[bl][nn][j] =
            *(const float4*)(x + ((size_t)(b0 + bl) * NIN + nbase + nn) * 8 + j * 4);
    }

    if (MODE >= 1) {
        // Wave w computes the squashed output vector for b0+w.
        int b = b0 + w;
        float4 v = *(const float4*)&s0[b * 256 + lane * 4];
        v.x *= 0.0625f; v.y *= 0.0625f; v.z *= 0.0625f; v.w *= 0.0625f;
        float sq = v.x*v.x + v.y*v.y + v.z*v.z + v.w*v.w;
        sq = dpp_add<0xB1>(sq);
        sq = dpp_add<0x4E>(sq);                  // sum over this k-row's 16 o's
        float sc = sq / (1.f + sq) * rsqrtf(sq);
        float4 o = make_float4(v.x*sc, v.y*sc, v.z*sc, v.w*sc);
        if (MODE == 2) {
            float4 u = *(const float4*)&s1[b * 256 + lane * 4];
            float q2 = u.x*u.x + u.y*u.y + u.z*u.z + u.w*u.w;
            q2 = dpp_add<0xB1>(q2);
            q2 = dpp_add<0x4E>(q2);
            float sc2 = q2 / (1.f + q2) * rsqrtf(q2);
            o.x = fmaf(u.x, sc2, o.x);
            o.y = fmaf(u.y, sc2, o.y);
            o.z = fmaf(u.z, sc2, o.z);
            o.w = fmaf(u.w, sc2, o.w);
        }
        ovs[w][lane] = o;
    }
    __syncthreads();

    // ov in regs: 16 VGPRs, loop-invariant.
    float4 ov[BGW];
    if (MODE >= 1) {
#pragma unroll
        for (int i = 0; i < BGW; ++i) ov[i] = ovs[i][lane];
    }

    float4 acc[BGW];
#pragma unroll
    for (int i = 0; i < BGW; ++i) acc[i] = make_float4(0.f, 0.f, 0.f, 0.f);

#pragma unroll
    for (int jj = 0; jj < NSTEP; ++jj) {
        const int n = nbase + w * NSTEP + jj;
        const float* wp = W + ((size_t)n * 16 + k) * 128 + o4 * 4;
        float4 wf[8];
#pragma unroll
        for (int d = 0; d < 8; ++d) wf[d] = *(const float4*)(wp + d * 16);

#pragma unroll
        for (int i = 0; i < BGW; ++i) {
            float4 xa = xt[i][w * NSTEP + jj][0];    // wave-uniform broadcast
            float4 xb = xt[i][w * NSTEP + jj][1];
            float4 h = make_float4(0.f, 0.f, 0.f, 0.f);
            h.x = fmaf(xa.x, wf[0].x, h.x); h.y = fmaf(xa.x, wf[0].y, h.y);
            h.z = fmaf(xa.x, wf[0].z, h.z); h.w = fmaf(xa.x, wf[0].w, h.w);
            h.x = fmaf(xa.y, wf[1].x, h.x); h.y = fmaf(xa.y, wf[1].y, h.y);
            h.z = fmaf(xa.y, wf[1].z, h.z); h.w = fmaf(xa.y, wf[1].w, h.w);
            h.x = fmaf(xa.z, wf[2].x, h.x); h.y = fmaf(xa.z, wf[2].y, h.y);
            h.z = fmaf(xa.z, wf[2].z, h.z); h.w = fmaf(xa.z, wf[2].w, h.w);
            h.x = fmaf(xa.w, wf[3].x, h.x); h.y = fmaf(xa.w, wf[3].y, h.y);
            h.z = fmaf(xa.w, wf[3].z, h.z); h.w = fmaf(xa.w, wf[3].w, h.w);
            h.x = fmaf(xb.x, wf[4].x, h.x); h.y = fmaf(xb.x, wf[4].y, h.y);
            h.z = fmaf(xb.x, wf[4].z, h.z); h.w = fmaf(xb.x, wf[4].w, h.w);
            h.x = fmaf(xb.y, wf[5].x, h.x); h.y = fmaf(xb.y, wf[5].y, h.y);
            h.z = fmaf(xb.y, wf[5].z, h.z); h.w = fmaf(xb.y, wf[5].w, h.w);
            h.x = fmaf(xb.z, wf[6].x, h.x); h.y = fmaf(xb.z, wf[6].y, h.y);
            h.z = fmaf(xb.z, wf[6].z, h.z); h.w = fmaf(xb.z, wf[6].w, h.w);
            h.x = fmaf(xb.w, wf[7].x, h.x); h.y = fmaf(xb.w, wf[7].y, h.y);
            h.z = fmaf(xb.w, wf[7].z, h.z); h.w = fmaf(xb.w, wf[7].w, h.w);

            if (MODE >= 1) {
                float part = h.x * ov[i].x;
                part = fmaf(h.y, ov[i].y, part);
                part = fmaf(h.z, ov[i].z, part);
                part = fmaf(h.w, ov[i].w, part);
                part = dpp_add<0xB1>(part);
                part = dpp_add<0x4E>(part);          // bias_k, quad-uniform
                // |bias| <~ 20 << 88: raw exp safe in f32 (validated R3-R8).
                float e = __expf(part);
                float es = e;
                es = dpp_add<0x124>(es);             // + ror4
                es = dpp_add<0x128>(es);             // -> sum of row's 4 k's
                es += __shfl_xor(es, 16);
                es += __shfl_xor(es, 32);            // full sum over 16 k's
                float c = __fdividef(e, es);
                h.x *= c; h.y *= c; h.z *= c; h.w *= c;
            }
            acc[i].x += h.x; acc[i].y += h.y; acc[i].z += h.z; acc[i].w += h.w;
        }
    }

    // Cross-wave reduce (4 waves hold different n-partials of same 4 b's).
#pragma unroll
    for (int i = 0; i < BGW; ++i) red[w][i][lane] = acc[i];
    __syncthreads();

    // 256 threads -> 256 float4 outputs; ONE contiguous 4 KB block partial.
    {
        int bl = tid >> 6, ln = tid & 63;
        float4 a  = red[0][bl][ln];
        float4 c1 = red[1][bl][ln];
        float4 c2 = red[2][bl][ln];
        float4 c3 = red[3][bl][ln];
        a.x += c1.x + c2.x + c3.x;
        a.y += c1.y + c2.y + c3.y;
        a.z += c1.z + c2.z + c3.z;
        a.w += c1.w + c2.w + c3.w;
        float* pbase = partial + (size_t)(blockIdx.y * GX + blockIdx.x) * (BGW * 256);
        *(float4*)&pbase[tid * 4] = a;
    }
}

// s[b][t] = sum over bx of partial[(by*GX+bx)*1024 + bl*256 + t], b=by*4+bl.
// 4 waves split the bx-range, LDS combine. SQUASH=1: squash over o, write out.
template<int SQUASH>
__global__ __launch_bounds__(256) void k_reduce(const float* __restrict__ partial,
                                                float* __restrict__ s) {
    const int b = blockIdx.x;
    const int by = b >> 2, bl = b & 3;
    const int lane = threadIdx.x & 63;
    const int w = threadIdx.x >> 6;
    const float* base = partial + ((size_t)by * GX) * (BGW * 256) + bl * 256 + lane * 4;
    float4 a = make_float4(0.f, 0.f, 0.f, 0.f);
#pragma unroll 8
    for (int xx = 0; xx < GX / 4; ++xx) {
        float4 v = *(const float4*)(base + (size_t)(w * (GX / 4) + xx) * (BGW * 256));
        a.x += v.x; a.y += v.y; a.z += v.z; a.w += v.w;
    }
    __shared__ float4 red[4][64];
    red[w][lane] = a;
    __syncthreads();
    if (w == 0) {
        float4 r1 = red[1][lane], r2 = red[2][lane], r3 = red[3][lane];
        a.x += r1.x + r2.x + r3.x;
        a.y += r1.y + r2.y + r3.y;
        a.z += r1.z + r2.z + r3.z;
        a.w += r1.w + r2.w + r3.w;
        if (SQUASH) {
            float sq = a.x*a.x + a.y*a.y + a.z*a.z + a.w*a.w;
            sq = dpp_add<0xB1>(sq);
            sq = dpp_add<0x4E>(sq);                  // sum over 16 o's of this k
            float sc = sq / (1.f + sq) * rsqrtf(sq);
            a.x *= sc; a.y *= sc; a.z *= sc; a.w *= sc;
        }
        *(float4*)&s[b * 256 + lane * 4] = a;
    }
}

extern "C" void kernel_launch(void* const* d_in, const int* in_sizes, int n_in,
                              void* d_out, int out_size, void* d_ws, size_t ws_size,
                              hipStream_t stream) {
    const float* x = (const float*)d_in[0];
    const float* W = (const float*)d_in[1];
    float* out = (float*)d_out;

    float* s0 = (float*)d_ws;                 // [64][256]
    float* s1 = s0 + B_ * 256;
    float* partial = s1 + B_ * 256;           // 2048 blocks x 4 KB = 8 MB

    dim3 grid(GX, GY);                        // (128, 16) = 2048 blocks

    k_pass<0><<<grid, 256, 0, stream>>>(x, W, nullptr, nullptr, partial);
    k_reduce<0><<<B_, 256, 0, stream>>>(partial, s0);
    k_pass<1><<<grid, 256, 0, stream>>>(x, W, s0, nullptr, partial);
    k_reduce<0><<<B_, 256, 0, stream>>>(partial, s1);
    k_pass<2><<<grid, 256, 0, stream>>>(x, W, s0, s1, partial);
    k_reduce<1><<<B_, 256, 0, stream>>>(partial, out);
}

// Round 11
// 133.164 us; speedup vs baseline: 2.8523x; 1.0504x over previous
//
#include <hip/hip_runtime.h>

// CapsuleBlock dynamic routing, MI355X — R10 (resubmit; R10 bench was an
// infra failure: GPU acquisition timeout, no data).
// x: [64, 2048, 8] f32; W: [2048, 16, 8, 16] f32; out: [64, 16, 16] f32.
// R9 post-mortem: inner loop was DS-PIPE-bound: 2 ds_read_b128 (x broadcast)
// + 2 shfl per pair ~= 13-15us of serialized per-CU LDS pipe per pass --
// explains why occupancy changes (R3/R4/R9) never helped.
// R10: x loads made wave-uniform via readfirstlane-derived addresses (scalar
// path, no LDS), xt staging + barrier removed, c folded into acc FMA.
// Only 2 shfl/pair remain on the DS pipe (~2.5us/CU).

#define B_    64
#define NIN   2048
#define NW    4                  // waves per block
#define BGW   4                  // b's per block (all waves share them)
#define NSTEP 4                  // n's per wave
#define NCB   (NW * NSTEP)       // 16 n per block
#define GX    (NIN / NCB)        // 128
#define GY    (B_ / BGW)         // 16

// v + dpp(v). CTRL: 0xB1 = quad_perm xor1, 0x4E = quad_perm xor2,
// 0x124 = row_ror:4, 0x128 = row_ror:8 (row = 16 lanes).
template<int CTRL>
__device__ __forceinline__ float dpp_add(float v) {
    int t = __builtin_amdgcn_update_dpp(0, __float_as_int(v), CTRL, 0xF, 0xF, true);
    return v + __int_as_float(t);
}

// MODE 0: s0 = sum_n hat                 (uniform c; 1/16 applied in MODE1/2)
// MODE 1: ov = squash(s0/16);            s1 = sum_n softmax_k(hat.ov)*hat
// MODE 2: ov = squash(s0/16)+squash(s1); s2 = sum_n softmax_k(hat.ov)*hat
template<int MODE>
__global__ __launch_bounds__(256) void k_pass(const float* __restrict__ x,
                                              const float* __restrict__ W,
                                              const float* __restrict__ s0,
                                              const float* __restrict__ s1,
                                              float* __restrict__ partial) {
    __shared__ float4 ovs[BGW][64];        // 4 KB
    __shared__ float4 red[NW][BGW][64];    // 16 KB

    const int tid  = threadIdx.x;
    const int lane = tid & 63;
    // wave index as a PROVABLY-uniform scalar: enables s_load for x.
    const int wu   = __builtin_amdgcn_readfirstlane(tid >> 6);
    const int k    = lane >> 2;
    const int o4   = lane & 3;
    const int nbase = blockIdx.x * NCB;
    const int b0    = blockIdx.y * BGW;

    if (MODE >= 1) {
        // Wave wu computes the squashed output vector for b0+wu.
        int b = b0 + wu;
        float4 v = *(const float4*)&s0[b * 256 + lane * 4];
        v.x *= 0.0625f; v.y *= 0.0625f; v.z *= 0.0625f; v.w *= 0.0625f;
        float sq = v.x*v.x + v.y*v.y + v.z*v.z + v.w*v.w;
        sq = dpp_add<0xB1>(sq);
        sq = dpp_add<0x4E>(sq);                  // sum over this k-row's 16 o's
        float sc = sq / (1.f + sq) * rsqrtf(sq);
        float4 o = make_float4(v.x*sc, v.y*sc, v.z*sc, v.w*sc);
        if (MODE == 2) {
            float4 u = *(const float4*)&s1[b * 256 + lane * 4];
            float q2 = u.x*u.x + u.y*u.y + u.z*u.z + u.w*u.w;
            q2 = dpp_add<0xB1>(q2);
            q2 = dpp_add<0x4E>(q2);
            float sc2 = q2 / (1.f + q2) * rsqrtf(q2);
            o.x = fmaf(u.x, sc2, o.x);
            o.y = fmaf(u.y, sc2, o.y);
            o.z = fmaf(u.z, sc2, o.z);
            o.w = fmaf(u.w, sc2, o.w);
        }
        ovs[wu][lane] = o;
        __syncthreads();
    }

    // ov in regs: 16 VGPRs, loop-invariant.
    float4 ov[BGW];
    if (MODE >= 1) {
#pragma unroll
        for (int i = 0; i < BGW; ++i) ov[i] = ovs[i][lane];
    }

    float4 acc[BGW];
#pragma unroll
    for (int i = 0; i < BGW; ++i) acc[i] = make_float4(0.f, 0.f, 0.f, 0.f);

#pragma unroll
    for (int jj = 0; jj < NSTEP; ++jj) {
        const int n = nbase + wu * NSTEP + jj;     // uniform scalar
        const float* wp = W + ((size_t)n * 16 + k) * 128 + o4 * 4;
        float4 wf[8];
#pragma unroll
        for (int d = 0; d < 8; ++d) wf[d] = *(const float4*)(wp + d * 16);

        // x scalars: address depends only on (b0, i, n) -> wave-uniform.
        // Compiler can lower these to s_load (SMEM pipe, zero DS traffic).
        const float* xp = x + ((size_t)b0 * NIN + n) * 8;
        float xs[BGW][8];
#pragma unroll
        for (int i = 0; i < BGW; ++i)
#pragma unroll
            for (int d = 0; d < 8; ++d)
                xs[i][d] = xp[(size_t)i * (NIN * 8) + d];

#pragma unroll
        for (int i = 0; i < BGW; ++i) {
            float4 h = make_float4(0.f, 0.f, 0.f, 0.f);
#pragma unroll
            for (int d = 0; d < 8; ++d) {
                h.x = fmaf(xs[i][d], wf[d].x, h.x);
                h.y = fmaf(xs[i][d], wf[d].y, h.y);
                h.z = fmaf(xs[i][d], wf[d].z, h.z);
                h.w = fmaf(xs[i][d], wf[d].w, h.w);
            }
            if (MODE >= 1) {
                float part = h.x * ov[i].x;
                part = fmaf(h.y, ov[i].y, part);
                part = fmaf(h.z, ov[i].z, part);
                part = fmaf(h.w, ov[i].w, part);
                part = dpp_add<0xB1>(part);
                part = dpp_add<0x4E>(part);          // bias_k, quad-uniform
                // |bias| <~ 20 << 88: raw exp safe in f32 (validated R3-R9).
                float e = __expf(part);
                float es = e;
                es = dpp_add<0x124>(es);             // + ror4
                es = dpp_add<0x128>(es);             // -> sum of row's 4 k's
                es += __shfl_xor(es, 16);
                es += __shfl_xor(es, 32);            // full sum over 16 k's
                float c = __fdividef(e, es);
                acc[i].x = fmaf(c, h.x, acc[i].x);
                acc[i].y = fmaf(c, h.y, acc[i].y);
                acc[i].z = fmaf(c, h.z, acc[i].z);
                acc[i].w = fmaf(c, h.w, acc[i].w);
            } else {
                acc[i].x += h.x; acc[i].y += h.y;
                acc[i].z += h.z; acc[i].w += h.w;
            }
        }
    }

    // Cross-wave reduce (4 waves hold different n-partials of same 4 b's).
#pragma unroll
    for (int i = 0; i < BGW; ++i) red[wu][i][lane] = acc[i];
    __syncthreads();

    // 256 threads -> 256 float4 outputs; ONE contiguous 4 KB block partial.
    {
        int bl = tid >> 6, ln = tid & 63;
        float4 a  = red[0][bl][ln];
        float4 c1 = red[1][bl][ln];
        float4 c2 = red[2][bl][ln];
        float4 c3 = red[3][bl][ln];
        a.x += c1.x + c2.x + c3.x;
        a.y += c1.y + c2.y + c3.y;
        a.z += c1.z + c2.z + c3.z;
        a.w += c1.w + c2.w + c3.w;
        float* pbase = partial + (size_t)(blockIdx.y * GX + blockIdx.x) * (BGW * 256);
        *(float4*)&pbase[tid * 4] = a;
    }
}

// s[b][t] = sum over bx of partial[(by*GX+bx)*1024 + bl*256 + t], b=by*4+bl.
// 4 waves split the bx-range, LDS combine. SQUASH=1: squash over o, write out.
template<int SQUASH>
__global__ __launch_bounds__(256) void k_reduce(const float* __restrict__ partial,
                                                float* __restrict__ s) {
    const int b = blockIdx.x;
    const int by = b >> 2, bl = b & 3;
    const int lane = threadIdx.x & 63;
    const int w = threadIdx.x >> 6;
    const float* base = partial + ((size_t)by * GX) * (BGW * 256) + bl * 256 + lane * 4;
    float4 a = make_float4(0.f, 0.f, 0.f, 0.f);
#pragma unroll 8
    for (int xx = 0; xx < GX / 4; ++xx) {
        float4 v = *(const float4*)(base + (size_t)(w * (GX / 4) + xx) * (BGW * 256));
        a.x += v.x; a.y += v.y; a.z += v.z; a.w += v.w;
    }
    __shared__ float4 red[4][64];
    red[w][lane] = a;
    __syncthreads();
    if (w == 0) {
        float4 r1 = red[1][lane], r2 = red[2][lane], r3 = red[3][lane];
        a.x += r1.x + r2.x + r3.x;
        a.y += r1.y + r2.y + r3.y;
        a.z += r1.z + r2.z + r3.z;
        a.w += r1.w + r2.w + r3.w;
        if (SQUASH) {
            float sq = a.x*a.x + a.y*a.y + a.z*a.z + a.w*a.w;
            sq = dpp_add<0xB1>(sq);
            sq = dpp_add<0x4E>(sq);                  // sum over 16 o's of this k
            float sc = sq / (1.f + sq) * rsqrtf(sq);
            a.x *= sc; a.y *= sc; a.z *= sc; a.w *= sc;
        }
        *(float4*)&s[b * 256 + lane * 4] = a;
    }
}

extern "C" void kernel_launch(void* const* d_in, const int* in_sizes, int n_in,
                              void* d_out, int out_size, void* d_ws, size_t ws_size,
                              hipStream_t stream) {
    const float* x = (const float*)d_in[0];
    const float* W = (const float*)d_in[1];
    float* out = (float*)d_out;

    float* s0 = (float*)d_ws;                 // [64][256]
    float* s1 = s0 + B_ * 256;
    float* partial = s1 + B_ * 256;           // 2048 blocks x 4 KB = 8 MB

    dim3 grid(GX, GY);                        // (128, 16) = 2048 blocks

    k_pass<0><<<grid, 256, 0, stream>>>(x, W, nullptr, nullptr, partial);
    k_reduce<0><<<B_, 256, 0, stream>>>(partial, s0);
    k_pass<1><<<grid, 256, 0, stream>>>(x, W, s0, nullptr, partial);
    k_reduce<0><<<B_, 256, 0, stream>>>(partial, s1);
    k_pass<2><<<grid, 256, 0, stream>>>(x, W, s0, s1, partial);
    k_reduce<1><<<B_, 256, 0, stream>>>(partial, out);
}